// Round 10
// baseline (48.283 us; speedup 1.0000x reference)
//
#include <hip/hip_runtime.h>

// SSIM map: refl-pad(1) + 3x3 avg-pool stencil, B=16 C=3 H=512 W=512 fp32.
// Ledger: R5 scalar 34.3 | R6 float4 36.8 | R7 NT 38.9 | R8 pipeline 33.6 |
// R9 dual-plane 33.5. Nothing saturated (VALU<=43%, HBM ~3.4TB/s, occ<=60%).
// R10 theory: bound on per-CU vmem issue / L1 lookups (6 overlapping load
// instrs/row). Fix: lane loads ONLY its center column (2 loads/row); left/
// right neighbors via __shfl_up/down; column reflection = select between
// the two shuffles. Wave covers 64 cols -> 62 outputs; 9 col-tiles.

#define HH 512
#define WW 512
#define ROWS 16          // rows per thread strip
#define TILE 62          // output cols per wave (64 loaded, 2 halo)
#define SSIM_C1 1e-4f    // 0.01^2
#define SSIM_C2 9e-4f    // 0.03^2

__global__ __launch_bounds__(256) void ssim_kernel(const float* __restrict__ x,
                                                   const float* __restrict__ y,
                                                   float* __restrict__ out) {
    const int lane  = threadIdx.x;                   // 0..63 (one wave in x)
    const int outc  = blockIdx.x * TILE + lane - 1;  // output col of this lane
    // center-column load address, clamped (clamped lanes' values are unused)
    const int lcol  = outc < 0 ? 0 : (outc > WW - 1 ? WW - 1 : outc);
    const int strip = blockIdx.y * 4 + threadIdx.y;
    const int row0  = strip * ROWS;
    const size_t po = (size_t)blockIdx.z * (size_t)(HH * WW);
    const float* xp = x + po;
    const float* yp = y + po;
    float* op       = out + po;

    const bool do_store = (lane >= 1) && (lane <= TILE) && (outc <= WW - 1);
    const bool c_lo = (outc == 0);        // left neighbor reflects to col 1
    const bool c_hi = (outc == WW - 1);   // right neighbor reflects to col 510

    const float inv9 = 1.0f / 9.0f;

    // 3-deep sliding window of horizontal row-sums for 5 quantities.
    float sx0, sy0, sxx0, syy0, sxy0;
    float sx1, sy1, sxx1, syy1, sxy1;

// 2 loads/row; neighbors via wave shuffles; reflection via select.
#define LOADROW(r, SX, SY, SXX, SYY, SXY) do {                      \
    int rr_ = (r) < 0 ? 1 : ((r) >= HH ? HH - 2 : (r));             \
    float xc_ = xp[(size_t)rr_ * WW + lcol];                        \
    float yc_ = yp[(size_t)rr_ * WW + lcol];                        \
    float xL_ = __shfl_up(xc_, 1);                                  \
    float xR_ = __shfl_down(xc_, 1);                                \
    float yL_ = __shfl_up(yc_, 1);                                  \
    float yR_ = __shfl_down(yc_, 1);                                \
    float xl_ = c_lo ? xR_ : xL_;                                   \
    float xr_ = c_hi ? xL_ : xR_;                                   \
    float yl_ = c_lo ? yR_ : yL_;                                   \
    float yr_ = c_hi ? yL_ : yR_;                                   \
    SX  = xl_ + xc_ + xr_;                                          \
    SY  = yl_ + yc_ + yr_;                                          \
    SXX = xl_*xl_ + xc_*xc_ + xr_*xr_;                              \
    SYY = yl_*yl_ + yc_*yc_ + yr_*yr_;                              \
    SXY = xl_*yl_ + xc_*yc_ + xr_*yr_;                              \
} while (0)

    // Prime rows row0-1 (reflected) and row0.
    LOADROW(row0 - 1, sx0, sy0, sxx0, syy0, sxy0);
    LOADROW(row0,     sx1, sy1, sxx1, syy1, sxy1);

    #pragma unroll 4
    for (int i = 0; i < ROWS; ++i) {
        const int r = row0 + i;
        float sx2, sy2, sxx2, syy2, sxy2;
        LOADROW(r + 1, sx2, sy2, sxx2, syy2, sxy2);

        const float sx  = sx0  + sx1  + sx2;
        const float sy  = sy0  + sy1  + sy2;
        const float sxx = sxx0 + sxx1 + sxx2;
        const float syy = syy0 + syy1 + syy2;
        const float sxy = sxy0 + sxy1 + sxy2;

        const float mux   = sx * inv9;
        const float muy   = sy * inv9;
        const float sigx  = sxx * inv9 - mux * mux;
        const float sigy  = syy * inv9 - muy * muy;
        const float sigxy = sxy * inv9 - mux * muy;

        const float n = (2.0f * mux * muy + SSIM_C1) * (2.0f * sigxy + SSIM_C2);
        const float d = (mux * mux + muy * muy + SSIM_C1) * (sigx + sigy + SSIM_C2);
        float v = (1.0f - n / (d + 1e-8f)) * 0.5f;
        v = fminf(fmaxf(v, 0.0f), 1.0f);

        if (do_store) op[(size_t)r * WW + outc] = v;

        sx0 = sx1;  sy0 = sy1;  sxx0 = sxx1;  syy0 = syy1;  sxy0 = sxy1;
        sx1 = sx2;  sy1 = sy2;  sxx1 = sxx2;  syy1 = syy2;  sxy1 = sxy2;
    }
#undef LOADROW
}

extern "C" void kernel_launch(void* const* d_in, const int* in_sizes, int n_in,
                              void* d_out, int out_size, void* d_ws, size_t ws_size,
                              hipStream_t stream) {
    const float* x = (const float*)d_in[0];
    const float* y = (const float*)d_in[1];
    float* out     = (float*)d_out;

    // 9 col-tiles (8*62=496 + final 16) x 8 strip-groups x 48 planes.
    // block (64,4): 4 independent waves, each owns one row strip.
    dim3 block(64, 4, 1);
    dim3 grid((WW + TILE - 1) / TILE, HH / (ROWS * 4), 48);  // (9, 8, 48)
    ssim_kernel<<<grid, block, 0, stream>>>(x, y, out);
}

// Round 11
// 32.128 us; speedup vs baseline: 1.5028x; 1.5028x over previous
//
#include <hip/hip_runtime.h>

// SSIM map: refl-pad(1) + 3x3 avg-pool stencil, B=16 C=3 H=512 W=512 fp32.
// Ledger: R5 34.3 | R6 f4 36.8 | R7 NT 38.9 | R8 pipe 33.6 | R9 dual 33.5 |
// R10 shfl 48.3. Memory-side levers falsified; plateau ~33.5us with
// VALUBusy ~45%. R11: cut VALU critical path — replace IEEE n/d division
// (~10 instrs) with v_rcp_f32 (error ~1e-7 << 3.9e-3 absmax) and force
// fma contraction in the horizontal/epilogue chains.

#define HH 512
#define WW 512
#define ROWS 16          // rows per thread; grid.y = HH/ROWS
#define SSIM_C1 1e-4f    // 0.01^2
#define SSIM_C2 9e-4f    // 0.03^2

__global__ __launch_bounds__(256) void ssim_kernel(const float* __restrict__ x,
                                                   const float* __restrict__ y,
                                                   float* __restrict__ out) {
    const int col   = blockIdx.x * 256 + threadIdx.x;   // 0..511
    const int row0  = blockIdx.y * ROWS;
    const size_t po = (size_t)blockIdx.z * (size_t)(HH * WW);
    const float* xp = x + po;
    const float* yp = y + po;
    float* op       = out + po;

    // reflection-pad(1) column neighbors
    const int cl = (col == 0)      ? 1      : col - 1;
    const int cr = (col == WW - 1) ? WW - 2 : col + 1;

    // 3-deep sliding window of horizontal row-sums for 5 quantities.
    float sx0, sy0, sxx0, syy0, sxy0;
    float sx1, sy1, sxx1, syy1, sxy1;

#define LOADROW(r, SX, SY, SXX, SYY, SXY) do {                      \
    int rr_ = (r) < 0 ? 1 : ((r) >= HH ? HH - 2 : (r));             \
    const float* xr_ = xp + rr_ * WW;                               \
    const float* yr_ = yp + rr_ * WW;                               \
    float xl_ = xr_[cl], xc_ = xr_[col], xv_ = xr_[cr];             \
    float yl_ = yr_[cl], yc_ = yr_[col], yv_ = yr_[cr];             \
    SX  = xl_ + xc_ + xv_;                                          \
    SY  = yl_ + yc_ + yv_;                                          \
    SXX = fmaf(xl_, xl_, fmaf(xc_, xc_, xv_ * xv_));                \
    SYY = fmaf(yl_, yl_, fmaf(yc_, yc_, yv_ * yv_));                \
    SXY = fmaf(xl_, yl_, fmaf(xc_, yc_, xv_ * yv_));                \
} while (0)

    // Prime rows row0-1 (reflected) and row0.
    LOADROW(row0 - 1, sx0, sy0, sxx0, syy0, sxy0);
    LOADROW(row0,     sx1, sy1, sxx1, syy1, sxy1);

    const float inv9 = 1.0f / 9.0f;

    #pragma unroll 4
    for (int i = 0; i < ROWS; ++i) {
        const int r = row0 + i;
        float sx2, sy2, sxx2, syy2, sxy2;
        LOADROW(r + 1, sx2, sy2, sxx2, syy2, sxy2);

        const float sx  = sx0  + sx1  + sx2;
        const float sy  = sy0  + sy1  + sy2;
        const float sxx = sxx0 + sxx1 + sxx2;
        const float syy = syy0 + syy1 + syy2;
        const float sxy = sxy0 + sxy1 + sxy2;

        const float mux   = sx * inv9;
        const float muy   = sy * inv9;
        // sig = s*inv9 - mu*mu as fused chains
        const float sigx  = fmaf(-mux, mux, sxx * inv9);
        const float sigy  = fmaf(-muy, muy, syy * inv9);
        const float sigxy = fmaf(-mux, muy, sxy * inv9);

        const float n = fmaf(mux + mux, muy, SSIM_C1) *
                        fmaf(2.0f, sigxy, SSIM_C2);
        const float d = fmaf(mux, mux, fmaf(muy, muy, SSIM_C1)) *
                        (sigx + sigy + SSIM_C2);

        // fast reciprocal: v_rcp_f32 (~1 ulp) instead of IEEE div (~10 instrs)
        const float rd = __builtin_amdgcn_rcpf(d + 1e-8f);
        float v = fmaf(n * rd, -0.5f, 0.5f);
        v = fminf(fmaxf(v, 0.0f), 1.0f);

        op[(size_t)r * WW + col] = v;

        sx0 = sx1;  sy0 = sy1;  sxx0 = sxx1;  syy0 = syy1;  sxy0 = sxy1;
        sx1 = sx2;  sy1 = sy2;  sxx1 = sxx2;  syy1 = syy2;  sxy1 = sxy2;
    }
#undef LOADROW
}

extern "C" void kernel_launch(void* const* d_in, const int* in_sizes, int n_in,
                              void* d_out, int out_size, void* d_ws, size_t ws_size,
                              hipStream_t stream) {
    const float* x = (const float*)d_in[0];
    const float* y = (const float*)d_in[1];
    float* out     = (float*)d_out;

    // B*C = 48 planes of 512x512
    dim3 block(256, 1, 1);
    dim3 grid(WW / 256, HH / ROWS, 48);   // (2, 32, 48) = 3072 blocks
    ssim_kernel<<<grid, block, 0, stream>>>(x, y, out);
}